// Round 14
// baseline (65.397 us; speedup 1.0000x reference)
//
#include <hip/hip_runtime.h>
#include <hip/hip_bf16.h>

// RotatedEmbedding: out[m,:] = W[ids[m],:] @ R  (M=16384, K=N=1024)
// Two-stage (fusion rejected r1/r2/r5/r6/r8; 8-phase graft rejected r13).
// prep (r7-exact): R->RT bf16 transposed || gather W->G bf16.
// GEMM: 256x128 tile, BK=32, 4 waves (wave-tile 128x64 = r7's per-wave shape),
//   A 3-ring 48K + B 3-ring 24K = 72 KB LDS -> 2 blocks/CU: two independent
//   barrier domains per CU so one block's MFMA/ds-reads cover the other's
//   stage/barrier stalls (m114) WITH r7's counted-vmcnt ledger (fixes r12's
//   vmcnt(0)-drain flaw). Pre-swizzled gload source (rule #21), 2-bit XOR
//   slot swizzle (2-way residual = free), XCD-bijective m-major swizzle (T1).

typedef __attribute__((ext_vector_type(4))) float f32x4;
typedef __attribute__((ext_vector_type(8))) short s16x8;
typedef __attribute__((ext_vector_type(2))) int i32x2;

#define DIM 1024
#define NTK 32  // K-tiles (BK=32)

__device__ __forceinline__ short f2bf(float f) {
  unsigned u = __float_as_uint(f);
  unsigned r = (u + 0x7FFFu + ((u >> 16) & 1u)) >> 16;  // RNE
  return (short)r;
}

__device__ __forceinline__ void gload_lds16(const void* g, void* l) {
  __builtin_amdgcn_global_load_lds((const __attribute__((address_space(1))) void*)g,
                                   (__attribute__((address_space(3))) void*)l, 16, 0, 0);
}

// blocks [0,1024): R [K][N] f32 -> RT [N][K] bf16; [1024,3072): gather G rows.
__global__ __launch_bounds__(256) void prep_kernel(const float* __restrict__ R,
                                                   short* __restrict__ RT,
                                                   const float* __restrict__ W,
                                                   const int* __restrict__ ids,
                                                   short* __restrict__ G) {
  const int b = blockIdx.x;
  const int t = threadIdx.x;
  if (b < 1024) {
    __shared__ float tile[32][33];
    const int bx = b & 31, by = b >> 5;
    const int tx = t & 31, ty = t >> 5;
#pragma unroll
    for (int i = 0; i < 4; ++i)
      tile[ty + i * 8][tx] = R[(size_t)(by * 32 + ty + i * 8) * DIM + bx * 32 + tx];
    __syncthreads();
#pragma unroll
    for (int i = 0; i < 4; ++i)
      RT[(size_t)(bx * 32 + ty + i * 8) * DIM + by * 32 + tx] = f2bf(tile[tx][ty + i * 8]);
  } else {  // G[m][k] = bf16(W[ids[m]][k]), coalesced f32x4 -> 4xbf16
    const int tid = (b - 1024) * 256 + t;
#pragma unroll
    for (int i = 0; i < 8; ++i) {
      const int g = tid + i * (2048 * 256);
      const int row = g >> 8;
      const int c4 = (g & 255) << 2;
      const f32x4 v = *(const f32x4*)(W + (size_t)ids[row] * DIM + c4);
      i32x2 p;
      p[0] = (int)(unsigned short)f2bf(v[0]) | ((int)f2bf(v[1]) << 16);
      p[1] = (int)(unsigned short)f2bf(v[2]) | ((int)f2bf(v[3]) << 16);
      *(i32x2*)(G + (size_t)g * 4) = p;
    }
  }
}

// GEMM: out[M,N] = G[M,K] * RT[N,K]^T. Grid 512 blocks x 256 threads.
// Dynamic LDS 73728 B: A ring 3 x 16384 @0; B ring 3 x 8192 @49152.
// Tile rows are 64 B (32 bf16 = BK); 16B slot s of row r holds logical
// chunk s ^ (r&3) ^ ((r>>2)&3)  [pre-swizzled source, rule #21].
__global__ __launch_bounds__(256, 2) void rot_embed_gemm(const short* __restrict__ G,
                                                         const short* __restrict__ RT,
                                                         float* __restrict__ out) {
  extern __shared__ char smem[];

  const int t = threadIdx.x;
  const int b = blockIdx.x;
  // T1: XCD-bijective (512 % 8 == 0), m-major: XCD x owns m-tiles
  // [x*8,(x+1)*8) with all 8 n-siblings -> A-panel 4 MB L2-resident.
  const int swz = (b & 7) * 64 + (b >> 3);
  const int m0 = (swz >> 3) * 256;
  const int n0 = (swz & 7) * 128;

  const int lane = t & 63;
  const int w = t >> 6;               // wave 0..3
  const int wm = w >> 1, wn = w & 1;  // wave-tile 128x64 at (wm*128, wn*64)
  const int fr = lane & 15, fq = lane >> 4;

  char* const ldsA = smem;           // 3 x 16384
  char* const ldsB = smem + 49152;   // 3 x 8192

  // Staging: instr j covers rows j*64 + (t>>2), slot t&3; logical chunk =
  // (t&3) ^ ((t>>2)&3) ^ ((t>>4)&3)  (j*64 row offset vanishes mod XOR bits).
  const int scol = ((t & 3) ^ ((t >> 2) & 3) ^ ((t >> 4) & 3)) * 8;  // bf16 elems
  const short* gA = G + (size_t)(m0 + (t >> 2)) * DIM + scol;
  const short* gB = RT + (size_t)(n0 + (t >> 2)) * DIM + scol;
  const int dOff = w * 1024;  // wave-uniform dest base (+lane*16 by HW)

#define STG(buf, kt)                                                        \
  {                                                                         \
    _Pragma("unroll") for (int j = 0; j < 4; ++j)                           \
        gload_lds16(gA + (size_t)(j * 64) * DIM + (kt) * 32,                \
                    ldsA + (buf) * 16384 + j * 4096 + dOff);                \
    _Pragma("unroll") for (int j = 0; j < 2; ++j)                           \
        gload_lds16(gB + (size_t)(j * 64) * DIM + (kt) * 32,                \
                    ldsB + (buf) * 8192 + j * 4096 + dOff);                 \
  }

  f32x4 acc[8][4];
#pragma unroll
  for (int i = 0; i < 8; ++i)
#pragma unroll
    for (int j = 0; j < 4; ++j) acc[i][j] = (f32x4)0.0f;

  // read slot (loop-invariant): chunk fq of row r; (r&3)=fr&3, ((r>>2)&3)=(fr>>2)&3
  const int sl = (fq ^ (fr & 3) ^ ((fr >> 2) & 3)) << 4;

  // prologue: 2 tiles in flight (12 vmem instrs); vmcnt(6) = tile 0 landed
  STG(0, 0);
  STG(1, 1);

  for (int kt = 0; kt < NTK; ++kt) {
    if (kt == NTK - 1)
      asm volatile("s_waitcnt vmcnt(0)" ::: "memory");
    else
      asm volatile("s_waitcnt vmcnt(6)" ::: "memory");  // tile kt landed
    asm volatile("s_waitcnt lgkmcnt(0)" ::: "memory");  // my prev reads drained
    __builtin_amdgcn_s_barrier();  // all waves: tile kt visible, old reads done

    if (kt + 2 < NTK) STG((kt + 2) % 3, kt + 2);

    const char* A = ldsA + (kt % 3) * 16384;
    const char* B = ldsB + (kt % 3) * 8192;
    s16x8 af[8], bfv[4];
#pragma unroll
    for (int i = 0; i < 8; ++i)
      af[i] = *(const s16x8*)(A + (wm * 128 + i * 16 + fr) * 64 + sl);
#pragma unroll
    for (int i = 0; i < 4; ++i)
      bfv[i] = *(const s16x8*)(B + (wn * 64 + i * 16 + fr) * 64 + sl);
    __builtin_amdgcn_s_setprio(1);
#pragma unroll
    for (int mi = 0; mi < 8; ++mi)
#pragma unroll
      for (int nj = 0; nj < 4; ++nj)
        acc[mi][nj] = __builtin_amdgcn_mfma_f32_16x16x32_bf16(af[mi], bfv[nj], acc[mi][nj], 0, 0, 0);
    __builtin_amdgcn_s_setprio(0);
  }

  // epilogue: D col=lane&15, row=(lane>>4)*4+reg (m89-verified); NT stores
#pragma unroll
  for (int mi = 0; mi < 8; ++mi)
#pragma unroll
    for (int nj = 0; nj < 4; ++nj) {
      float* op = out + (size_t)(m0 + wm * 128 + mi * 16 + fq * 4) * DIM +
                  (n0 + wn * 64 + nj * 16 + fr);
#pragma unroll
      for (int r = 0; r < 4; ++r)
        __builtin_nontemporal_store(acc[mi][nj][r], op + (size_t)r * DIM);
    }
#undef STG
}

extern "C" void kernel_launch(void* const* d_in, const int* in_sizes, int n_in,
                              void* d_out, int out_size, void* d_ws, size_t ws_size,
                              hipStream_t stream) {
  const int* ids = (const int*)d_in[0];    // [4,4096] int32
  const float* W = (const float*)d_in[1];  // [50257,1024] f32
  const float* R = (const float*)d_in[2];  // [1024,1024] f32
  float* out = (float*)d_out;              // [4,4096,1024] f32
  short* RT = (short*)d_ws;                // 2 MB bf16 R^T
  short* G = (short*)d_ws + (size_t)DIM * DIM;  // 32 MB bf16 gathered rows

  prep_kernel<<<dim3(3072), dim3(256), 0, stream>>>(R, RT, W, ids, G);
  rot_embed_gemm<<<dim3(512), dim3(256), 73728, stream>>>(G, RT, out);
}

// Round 15
// 62.526 us; speedup vs baseline: 1.0459x; 1.0459x over previous
//
#include <hip/hip_runtime.h>
#include <hip/hip_bf16.h>

// RotatedEmbedding: out[m,:] = W[ids[m],:] @ R  (M=16384, K=N=1024)
// == r7 (best: 57.4us) with exactly ONE loop change: s_setprio REMOVED from
// the MFMA cluster (m190: setprio hurts lockstep GEMM by starving the
// co-resident wave's ds_read issue -> kills cross-wave LDS||MFMA overlap),
// plus nontemporal epilogue stores.
// Stage 1 prep: R->RT bf16 transposed || gather W rows -> G bf16.
// Stage 2 GEMM: 256x256 tile, BK=64, NT=16, 8 waves (wave-tile 128x64),
//   A 3-ring / B 2-ring = 160 KB LDS, global_load_lds w/ pre-swizzled source
//   (slot = chunk ^ (row&7)), counted vmcnt(4) ledger, XCD swizzle.

typedef __attribute__((ext_vector_type(4))) float f32x4;
typedef __attribute__((ext_vector_type(8))) short s16x8;
typedef __attribute__((ext_vector_type(2))) int i32x2;

#define DIM 1024
#define NT 16  // K-tiles (BK=64)

__device__ __forceinline__ short f2bf(float f) {
  unsigned u = __float_as_uint(f);
  unsigned r = (u + 0x7FFFu + ((u >> 16) & 1u)) >> 16;  // RNE
  return (short)r;
}

__device__ __forceinline__ void gload_lds16(const void* g, void* l) {
  __builtin_amdgcn_global_load_lds((const __attribute__((address_space(1))) void*)g,
                                   (__attribute__((address_space(3))) void*)l, 16, 0, 0);
}

// blocks [0,1024): R [K][N] f32 -> RT [N][K] bf16; [1024,3072): gather G rows.
__global__ __launch_bounds__(256) void prep_kernel(const float* __restrict__ R,
                                                   short* __restrict__ RT,
                                                   const float* __restrict__ W,
                                                   const int* __restrict__ ids,
                                                   short* __restrict__ G) {
  const int b = blockIdx.x;
  const int t = threadIdx.x;
  if (b < 1024) {
    __shared__ float tile[32][33];
    const int bx = b & 31, by = b >> 5;
    const int tx = t & 31, ty = t >> 5;
#pragma unroll
    for (int i = 0; i < 4; ++i)
      tile[ty + i * 8][tx] = R[(size_t)(by * 32 + ty + i * 8) * DIM + bx * 32 + tx];
    __syncthreads();
#pragma unroll
    for (int i = 0; i < 4; ++i)
      RT[(size_t)(bx * 32 + ty + i * 8) * DIM + by * 32 + tx] = f2bf(tile[tx][ty + i * 8]);
  } else {  // G[m][k] = bf16(W[ids[m]][k]), coalesced f32x4 -> 4xbf16
    const int tid = (b - 1024) * 256 + t;
#pragma unroll
    for (int i = 0; i < 8; ++i) {
      const int g = tid + i * (2048 * 256);
      const int row = g >> 8;
      const int c4 = (g & 255) << 2;
      const f32x4 v = *(const f32x4*)(W + (size_t)ids[row] * DIM + c4);
      i32x2 p;
      p[0] = (int)(unsigned short)f2bf(v[0]) | ((int)f2bf(v[1]) << 16);
      p[1] = (int)(unsigned short)f2bf(v[2]) | ((int)f2bf(v[3]) << 16);
      *(i32x2*)(G + (size_t)g * 4) = p;
    }
  }
}

// GEMM: out[M,N] = G[M,K] * RT[N,K]^T. Grid 256 x 512 threads.
// Dynamic LDS 160 KB: A bufs x3 @ 0/32K/64K, B bufs x2 @ 96K/128K.
// Tile layout: 256 rows x 64 bf16 (128 B rows); 16B slot s holds logical
// chunk s ^ (row&7)  [pre-swizzled source, rule #21].
__global__ __launch_bounds__(512, 2) void rot_embed_gemm(const short* __restrict__ G,
                                                         const short* __restrict__ RT,
                                                         float* __restrict__ out) {
  extern __shared__ char smem[];

  const int t = threadIdx.x;
  const int b = blockIdx.x;
  // T1: XCD-bijective (256 blocks): XCD x -> m-panels [x*8,(x+1)*8), all 4 n
  const int swz = (b & 7) * 32 + (b >> 3);
  const int m0 = (swz >> 2) * 256;
  const int n0 = (swz & 3) * 256;

  const int lane = t & 63;
  const int w = t >> 6;
  const int wm = w >> 2, wn = w & 3;
  const int fr = lane & 15, fq = lane >> 4;

  char* const ldsA = smem;
  char* const ldsB = smem + 98304;

  // Staging: instr j covers LDS rows j*64 + w*8 + (lane>>3), slot lane&7.
  const int srow = w * 8 + (lane >> 3);
  const int sch = ((lane & 7) ^ (lane >> 3)) * 8;
  const short* gA = G + (size_t)(m0 + srow) * DIM + sch;
  const short* gB = RT + (size_t)(n0 + srow) * DIM + sch;
  const int ldsOff = w * 1024;

#define STA(buf, kt)                                                        \
  {                                                                         \
    _Pragma("unroll") for (int j = 0; j < 4; ++j)                           \
        gload_lds16(gA + (size_t)j * 64 * DIM + (kt) * 64,                  \
                    ldsA + (buf) * 32768 + j * 8192 + ldsOff);              \
  }
#define STB(buf, kt)                                                        \
  {                                                                         \
    _Pragma("unroll") for (int j = 0; j < 4; ++j)                           \
        gload_lds16(gB + (size_t)j * 64 * DIM + (kt) * 64,                  \
                    ldsB + (buf) * 32768 + j * 8192 + ldsOff);              \
  }

  f32x4 acc[8][4];
#pragma unroll
  for (int i = 0; i < 8; ++i)
#pragma unroll
    for (int j = 0; j < 4; ++j) acc[i][j] = (f32x4)0.0f;

  // prologue: A0, B0, A1 (A1 last so steady vmcnt(4) leaves only it)
  STA(0, 0);
  STB(0, 0);
  STA(1, 1);

  int bA = 0, bB = 0;
  for (int kt = 0; kt < NT; ++kt) {
    if (kt == NT - 1)
      asm volatile("s_waitcnt vmcnt(0)" ::: "memory");
    else
      asm volatile("s_waitcnt vmcnt(4)" ::: "memory");  // tile kt (A+B) landed
    asm volatile("s_waitcnt lgkmcnt(0)" ::: "memory");  // prev ds_reads drained
    __builtin_amdgcn_s_barrier();

    // issue order: B(kt+1) first, A(kt+2) last (keeps ledger exact)
    if (kt + 1 < NT) STB(bB ^ 1, kt + 1);
    if (kt + 2 < NT) { const int nb = (bA + 2 >= 3) ? bA - 1 : bA + 2; STA(nb, kt + 2); }

    const char* A = ldsA + bA * 32768;
    const char* B = ldsB + bB * 32768;
#pragma unroll
    for (int kk = 0; kk < 2; ++kk) {
      const int sl = ((fq + 4 * kk) ^ (fr & 7)) << 4;  // swizzled 16B slot
      s16x8 af[8], bfv[4];
#pragma unroll
      for (int mi = 0; mi < 8; ++mi)
        af[mi] = *(const s16x8*)(A + (wm * 128 + mi * 16 + fr) * 128 + sl);
#pragma unroll
      for (int nj = 0; nj < 4; ++nj)
        bfv[nj] = *(const s16x8*)(B + (wn * 64 + nj * 16 + fr) * 128 + sl);
      // NO setprio here (m190: starves co-wave ds_read issue in lockstep GEMM)
#pragma unroll
      for (int mi = 0; mi < 8; ++mi)
#pragma unroll
        for (int nj = 0; nj < 4; ++nj)
          acc[mi][nj] = __builtin_amdgcn_mfma_f32_16x16x32_bf16(af[mi], bfv[nj], acc[mi][nj], 0, 0, 0);
    }

    bA = (bA + 1 == 3) ? 0 : bA + 1;
    bB ^= 1;
  }

  // epilogue: D col=lane&15, row=(lane>>4)*4+reg (m89-verified); NT stores
#pragma unroll
  for (int mi = 0; mi < 8; ++mi)
#pragma unroll
    for (int nj = 0; nj < 4; ++nj) {
      float* op = out + (size_t)(m0 + wm * 128 + mi * 16 + fq * 4) * DIM +
                  (n0 + wn * 64 + nj * 16 + fr);
#pragma unroll
      for (int r = 0; r < 4; ++r)
        __builtin_nontemporal_store(acc[mi][nj][r], op + (size_t)r * DIM);
    }
#undef STA
#undef STB
}

extern "C" void kernel_launch(void* const* d_in, const int* in_sizes, int n_in,
                              void* d_out, int out_size, void* d_ws, size_t ws_size,
                              hipStream_t stream) {
  const int* ids = (const int*)d_in[0];    // [4,4096] int32
  const float* W = (const float*)d_in[1];  // [50257,1024] f32
  const float* R = (const float*)d_in[2];  // [1024,1024] f32
  float* out = (float*)d_out;              // [4,4096,1024] f32
  short* RT = (short*)d_ws;                // 2 MB bf16 R^T
  short* G = (short*)d_ws + (size_t)DIM * DIM;  // 32 MB bf16 gathered rows

  prep_kernel<<<dim3(3072), dim3(256), 0, stream>>>(R, RT, W, ids, G);
  rot_embed_gemm<<<dim3(256), dim3(512), 163840, stream>>>(G, RT, out);
}